// Round 12
// baseline (1277.676 us; speedup 1.0000x reference)
//
#include <hip/hip_runtime.h>
#include <cstdint>

// ODEBlock: 16 RK4 steps of f(t,y) = tanh(y@W1 + b1 + t) @ W2 + b2
// B=1024 (M), D=512, H=2048. bf16 MFMA GEMMs, fp32 state/epilogues.
// R12 = R11 (best: 1249us) + ONE change: LDS-shuffle epilogue in both GEMMs.
// Before: 16 scalar global_store_short/thread (4x 32B segments per wave-store,
// 64 L2 transactions/wave). After: stage tile in LDS (stride-72 rows = 2-way
// max bank aliasing, free per m136), read back ushort8, 2x store_dwordx4per
// thread (full 128B lines, 16 transactions/wave). Same values, same order ->
// bit-identical output (absmax must stay exactly 0.03125).

typedef __bf16 bf16x8 __attribute__((ext_vector_type(8)));
typedef float f32x4 __attribute__((ext_vector_type(4)));

#define AS1 __attribute__((address_space(1)))
#define AS3 __attribute__((address_space(3)))

#define MDIM 1024
#define DDIM 512
#define HDIM 2048

#define GEMM_LDS (64 * 1024)   // sA 2x16KB + sB 2x16KB (epilogue reuses sA)

__device__ __forceinline__ void async_copy16(const void* g, void* lds) {
  __builtin_amdgcn_global_load_lds((const AS1 void*)g, (AS3 void*)lds, 16, 0, 0);
}

__device__ __forceinline__ unsigned short f32_to_bf16(float f) {
  union { float f; unsigned u; } c; c.f = f;
  unsigned u = c.u + 0x7FFFu + ((c.u >> 16) & 1u);   // RNE
  return (unsigned short)(u >> 16);
}

__device__ __forceinline__ float bf16_to_f32(unsigned short h) {
  union { unsigned u; float f; } c; c.u = ((unsigned)h) << 16;
  return c.f;
}

__device__ __forceinline__ float tanh_fast(float x) {
  float a = __builtin_fabsf(x);
  float e = __expf(-2.0f * a);                        // in (0,1], no overflow
  float r = (1.0f - e) * __builtin_amdgcn_rcpf(1.0f + e);
  return __builtin_copysignf(r, x);
}

// ---- transpose + f32->bf16: out[c*R + r] = bf16(in[r*C + c]) --------------
__global__ __launch_bounds__(256) void transpose_bf16_kernel(
    const float* __restrict__ in, unsigned short* __restrict__ out, int R, int C) {
  __shared__ float tile[64][65];
  int nbc = C >> 6;
  int br = blockIdx.x / nbc, bc = blockIdx.x % nbc;
  int r0 = br * 64, c0 = bc * 64;
  int tr = threadIdx.x >> 6, tc = threadIdx.x & 63;
  for (int i = 0; i < 16; ++i) {
    int row = i * 4 + tr;
    tile[row][tc] = in[(r0 + row) * C + c0 + tc];
  }
  __syncthreads();
  for (int i = 0; i < 16; ++i) {
    int row = i * 4 + tr;
    out[(c0 + row) * R + r0 + tc] = f32_to_bf16(tile[tc][row]);
  }
}

// ---- init: y = x (fp32, lives in d_out), arg = bf16(x) --------------------
__global__ __launch_bounds__(256) void init_kernel(
    const float* __restrict__ x, float* __restrict__ y,
    unsigned short* __restrict__ arg) {
  int i = blockIdx.x * 256 + threadIdx.x;
  float v = x[i];
  y[i] = v;
  arg[i] = f32_to_bf16(v);
}

// ---- GEMM1: H = tanh(arg[1024,512] @ W1 + b1 + t) -------------------------
// W1T [2048,512] bf16 (K-contig). Tile 64x64, BK=128, 4 K-iters, grid 512
// (2 blocks/CU), 4 waves 2x2, wave 32x32, LDS dbuf 64KB. XOR-swizzled
// staging. Epilogue: LDS-shuffle to coalesced ushort8 stores.
__global__ __launch_bounds__(256, 2) void gemm1_kernel(
    const unsigned short* __restrict__ A,    // arg bf16 [1024,512]
    const unsigned short* __restrict__ Bt,   // W1T bf16 [2048,512]
    const float* __restrict__ b1, float tval,
    unsigned short* __restrict__ H)          // [1024,2048] bf16
{
  extern __shared__ char ldsbuf[];
  bf16x8* sA = (bf16x8*)ldsbuf;              // 2 x 1024 units (32KB)
  bf16x8* sB = (bf16x8*)(ldsbuf + 32768);    // 2 x 1024 units (32KB)
  unsigned short* sE = (unsigned short*)ldsbuf;  // epilogue tile 64x72 ushort
  const int K = DDIM;
  const int NITER = 4;            // 512 / 128
  int bid = blockIdx.x;
  int bm = bid >> 5;              // 0..15
  int bn = bid & 31;              // 0..31
  int tid = threadIdx.x;
  int lane = tid & 63;
  int wid = tid >> 6;
  int l15 = lane & 15;
  int l4 = lane >> 4;
  int wm = (wid >> 1) * 32;
  int wn = (wid & 1) * 32;
  int sw = l15 & 7;               // read-side swizzle (row & 7)

  // staging: 4 units per thread per matrix (1024 units = 64 rows x 16 slots)
  const unsigned short* gA[4];
  const unsigned short* gB[4];
#pragma unroll
  for (int i = 0; i < 4; ++i) {
    int u = tid + i * 256, r = u >> 4, s = u & 15;
    int koff = ((s ^ (r & 7)) * 8);
    gA[i] = A + (size_t)(bm * 64 + r) * K + koff;
    gB[i] = Bt + (size_t)(bn * 64 + r) * K + koff;
  }
  f32x4 acc[2][2] = {};

#pragma unroll
  for (int i = 0; i < 4; ++i) {
    async_copy16(gA[i], &sA[tid + i * 256]);
    async_copy16(gB[i], &sB[tid + i * 256]);
  }

#pragma unroll 1
  for (int kt = 0; kt < NITER; ++kt) {
    int cur = kt & 1;
    __syncthreads();
    if (kt + 1 < NITER) {
      int nxt = cur ^ 1;
      int off = (kt + 1) * 128;
#pragma unroll
      for (int i = 0; i < 4; ++i) {
        async_copy16(gA[i] + off, &sA[nxt * 1024 + tid + i * 256]);
        async_copy16(gB[i] + off, &sB[nxt * 1024 + tid + i * 256]);
      }
    }
#pragma unroll
    for (int ks = 0; ks < 4; ++ks) {
      int kg = (ks * 4 + l4) ^ sw;
      bf16x8 af[2], bfr[2];
#pragma unroll
      for (int i = 0; i < 2; ++i)
        af[i] = sA[cur * 1024 + (wm + i * 16 + l15) * 16 + kg];
#pragma unroll
      for (int j = 0; j < 2; ++j)
        bfr[j] = sB[cur * 1024 + (wn + j * 16 + l15) * 16 + kg];
#pragma unroll
      for (int i = 0; i < 2; ++i)
#pragma unroll
        for (int j = 0; j < 2; ++j)
          acc[i][j] = __builtin_amdgcn_mfma_f32_16x16x32_bf16(
              af[i], bfr[j], acc[i][j], 0, 0, 0);
    }
  }
  // ---- epilogue via LDS shuffle ----
  // local tile coords: lrow = wm + i*16 + l4*4 + r, lcol = wn + j*16 + l15
  int col0 = bn * 64 + wn + l15;
  float bias[2];
  for (int j = 0; j < 2; ++j) bias[j] = b1[col0 + j * 16] + tval;
  __syncthreads();   // K-loop LDS reads done; safe to reuse sA region
#pragma unroll
  for (int i = 0; i < 2; ++i)
#pragma unroll
    for (int r = 0; r < 4; ++r) {
      int lrow = wm + i * 16 + l4 * 4 + r;
#pragma unroll
      for (int j = 0; j < 2; ++j)
        sE[lrow * 72 + wn + j * 16 + l15] =
            f32_to_bf16(tanh_fast(acc[i][j][r] + bias[j]));
    }
  __syncthreads();
  // read back coalesced: 2 chunks of ushort8 per thread
#pragma unroll
  for (int c = 0; c < 2; ++c) {
    int u = c * 256 + tid;         // 0..511
    int row = u >> 3, cg = u & 7;
    bf16x8 v = *(const bf16x8*)(sE + row * 72 + cg * 8);
    *(bf16x8*)(H + (size_t)(bm * 64 + row) * HDIM + bn * 64 + cg * 8) = v;
  }
}

// ---- GEMM2 split-K: part[s] = H[:, s*512:(s+1)*512] @ W2T'[:, chunk] ------
// W2T [512,2048] bf16. Tile 64x64, BK=128, 4 iters per 512-K chunk,
// splitK=4, grid 512. Partials bf16, LDS-shuffle epilogue.
__global__ __launch_bounds__(256, 2) void gemm2_kernel(
    const unsigned short* __restrict__ A,    // H bf16 [1024,2048]
    const unsigned short* __restrict__ Bt,   // W2T bf16 [512,2048]
    unsigned short* __restrict__ part)       // [4][1024,512] bf16
{
  extern __shared__ char ldsbuf[];
  bf16x8* sA = (bf16x8*)ldsbuf;
  bf16x8* sB = (bf16x8*)(ldsbuf + 32768);
  unsigned short* sE = (unsigned short*)ldsbuf;
  const int K = HDIM;
  const int NITER = 4;                 // 512 K-chunk / 128
  int bid = blockIdx.x;
  int s = bid >> 7;                    // split-K index 0..3
  int rem = bid & 127;
  int bm = rem >> 3;                   // 0..15
  int bn = rem & 7;                    // 0..7
  int tid = threadIdx.x;
  int lane = tid & 63;
  int wid = tid >> 6;
  int l15 = lane & 15;
  int l4 = lane >> 4;
  int wm = (wid >> 1) * 32;
  int wn = (wid & 1) * 32;
  int sw = l15 & 7;
  int k0 = s * 512;

  const unsigned short* gA[4];
  const unsigned short* gB[4];
#pragma unroll
  for (int i = 0; i < 4; ++i) {
    int u = tid + i * 256, r = u >> 4, sl = u & 15;
    int koff = ((sl ^ (r & 7)) * 8);
    gA[i] = A + (size_t)(bm * 64 + r) * K + k0 + koff;
    gB[i] = Bt + (size_t)(bn * 64 + r) * K + k0 + koff;
  }
  f32x4 acc[2][2] = {};

#pragma unroll
  for (int i = 0; i < 4; ++i) {
    async_copy16(gA[i], &sA[tid + i * 256]);
    async_copy16(gB[i], &sB[tid + i * 256]);
  }

#pragma unroll 1
  for (int kt = 0; kt < NITER; ++kt) {
    int cur = kt & 1;
    __syncthreads();
    if (kt + 1 < NITER) {
      int nxt = cur ^ 1;
      int off = (kt + 1) * 128;
#pragma unroll
      for (int i = 0; i < 4; ++i) {
        async_copy16(gA[i] + off, &sA[nxt * 1024 + tid + i * 256]);
        async_copy16(gB[i] + off, &sB[nxt * 1024 + tid + i * 256]);
      }
    }
#pragma unroll
    for (int ks = 0; ks < 4; ++ks) {
      int kg = (ks * 4 + l4) ^ sw;
      bf16x8 af[2], bfr[2];
#pragma unroll
      for (int i = 0; i < 2; ++i)
        af[i] = sA[cur * 1024 + (wm + i * 16 + l15) * 16 + kg];
#pragma unroll
      for (int j = 0; j < 2; ++j)
        bfr[j] = sB[cur * 1024 + (wn + j * 16 + l15) * 16 + kg];
#pragma unroll
      for (int i = 0; i < 2; ++i)
#pragma unroll
        for (int j = 0; j < 2; ++j)
          acc[i][j] = __builtin_amdgcn_mfma_f32_16x16x32_bf16(
              af[i], bfr[j], acc[i][j], 0, 0, 0);
    }
  }
  // ---- epilogue via LDS shuffle (bf16 partials) ----
  __syncthreads();
#pragma unroll
  for (int i = 0; i < 2; ++i)
#pragma unroll
    for (int r = 0; r < 4; ++r) {
      int lrow = wm + i * 16 + l4 * 4 + r;
#pragma unroll
      for (int j = 0; j < 2; ++j)
        sE[lrow * 72 + wn + j * 16 + l15] = f32_to_bf16(acc[i][j][r]);
    }
  __syncthreads();
  unsigned short* P = part + (size_t)s * (MDIM * DDIM);
#pragma unroll
  for (int c = 0; c < 2; ++c) {
    int u = c * 256 + tid;
    int row = u >> 3, cg = u & 7;
    bf16x8 v = *(const bf16x8*)(sE + row * 72 + cg * 8);
    *(bf16x8*)(P + (size_t)(bm * 64 + row) * DDIM + bn * 64 + cg * 8) = v;
  }
}

// ---- combine + RK4 epilogue (bf16 partials -> fp32 sum) -------------------
// k = p0+p1+p2+p3 + b2   (partials bf16, converted to f32, summed in f32)
// mode 0: kacc = k;            arg = bf16(y + dt/2*k)
// mode 1: kacc += 2k;          arg = bf16(y + dt/2*k)
// mode 2: kacc += 2k;          arg = bf16(y + dt*k)
// mode 3: y += dt/6*(kacc+k);  arg = bf16(y_new)
__global__ __launch_bounds__(256) void combine_rk4_kernel(
    const unsigned short* __restrict__ part,  // [4][1024*512] bf16
    const float* __restrict__ b2,
    float* __restrict__ y, float* __restrict__ kacc,
    unsigned short* __restrict__ arg, int mode, float dt)
{
  int t = blockIdx.x * 256 + threadIdx.x;    // 0..131071
  int base = t * 4;
  int col = base & (DDIM - 1);
  const ushort4* p0 = (const ushort4*)(part);
  const ushort4* p1 = (const ushort4*)(part + MDIM * DDIM);
  const ushort4* p2 = (const ushort4*)(part + 2 * MDIM * DDIM);
  const ushort4* p3 = (const ushort4*)(part + 3 * MDIM * DDIM);
  ushort4 a = p0[t], b = p1[t], c = p2[t], d = p3[t];
  float4 bb = *(const float4*)(b2 + col);
  float4 k;
  k.x = bf16_to_f32(a.x) + bf16_to_f32(b.x) + bf16_to_f32(c.x) + bf16_to_f32(d.x) + bb.x;
  k.y = bf16_to_f32(a.y) + bf16_to_f32(b.y) + bf16_to_f32(c.y) + bf16_to_f32(d.y) + bb.y;
  k.z = bf16_to_f32(a.z) + bf16_to_f32(b.z) + bf16_to_f32(c.z) + bf16_to_f32(d.z) + bb.z;
  k.w = bf16_to_f32(a.w) + bf16_to_f32(b.w) + bf16_to_f32(c.w) + bf16_to_f32(d.w) + bb.w;
  float4 yv = *(const float4*)(y + base);
  float4 argv;
  if (mode == 0) {
    *(float4*)(kacc + base) = k;
    float h = 0.5f * dt;
    argv.x = yv.x + h * k.x; argv.y = yv.y + h * k.y;
    argv.z = yv.z + h * k.z; argv.w = yv.w + h * k.w;
  } else if (mode == 1) {
    float4 ka = *(const float4*)(kacc + base);
    ka.x += 2.0f * k.x; ka.y += 2.0f * k.y; ka.z += 2.0f * k.z; ka.w += 2.0f * k.w;
    *(float4*)(kacc + base) = ka;
    float h = 0.5f * dt;
    argv.x = yv.x + h * k.x; argv.y = yv.y + h * k.y;
    argv.z = yv.z + h * k.z; argv.w = yv.w + h * k.w;
  } else if (mode == 2) {
    float4 ka = *(const float4*)(kacc + base);
    ka.x += 2.0f * k.x; ka.y += 2.0f * k.y; ka.z += 2.0f * k.z; ka.w += 2.0f * k.w;
    *(float4*)(kacc + base) = ka;
    argv.x = yv.x + dt * k.x; argv.y = yv.y + dt * k.y;
    argv.z = yv.z + dt * k.z; argv.w = yv.w + dt * k.w;
  } else {
    float4 ka = *(const float4*)(kacc + base);
    float sx = dt * (1.0f / 6.0f);
    argv.x = yv.x + sx * (ka.x + k.x); argv.y = yv.y + sx * (ka.y + k.y);
    argv.z = yv.z + sx * (ka.z + k.z); argv.w = yv.w + sx * (ka.w + k.w);
    *(float4*)(y + base) = argv;
  }
  ushort4 av;
  av.x = f32_to_bf16(argv.x); av.y = f32_to_bf16(argv.y);
  av.z = f32_to_bf16(argv.z); av.w = f32_to_bf16(argv.w);
  *(ushort4*)(arg + base) = av;
}

extern "C" void kernel_launch(void* const* d_in, const int* in_sizes, int n_in,
                              void* d_out, int out_size, void* d_ws, size_t ws_size,
                              hipStream_t stream) {
  (void)in_sizes; (void)n_in; (void)out_size; (void)ws_size;
  const float* x  = (const float*)d_in[0];   // [1024,512]
  const float* W1 = (const float*)d_in[1];   // [512,2048]
  const float* b1 = (const float*)d_in[2];   // [2048]
  const float* W2 = (const float*)d_in[3];   // [2048,512]
  const float* b2 = (const float*)d_in[4];   // [512]
  float* y = (float*)d_out;                  // fp32 state lives in d_out

  char* ws = (char*)d_ws;
  unsigned short* W1T  = (unsigned short*)(ws);                    // 2MB  [2048,512] bf16
  unsigned short* W2T  = (unsigned short*)(ws + (2u << 20));       // 2MB  [512,2048] bf16
  unsigned short* Hbuf = (unsigned short*)(ws + (4u << 20));       // 4MB  [1024,2048] bf16
  unsigned short* arg  = (unsigned short*)(ws + (8u << 20));       // 1MB  [1024,512] bf16
  float*          kacc = (float*)(ws + (9u << 20));                // 2MB  [1024,512] f32
  unsigned short* part = (unsigned short*)(ws + (11u << 20));      // 4MB  [4][1024,512] bf16
  // total 15MB

  hipFuncSetAttribute((const void*)gemm1_kernel,
                      hipFuncAttributeMaxDynamicSharedMemorySize, GEMM_LDS);
  hipFuncSetAttribute((const void*)gemm2_kernel,
                      hipFuncAttributeMaxDynamicSharedMemorySize, GEMM_LDS);

  transpose_bf16_kernel<<<256, 256, 0, stream>>>(W1, W1T, DDIM, HDIM);
  transpose_bf16_kernel<<<256, 256, 0, stream>>>(W2, W2T, HDIM, DDIM);
  init_kernel<<<MDIM * DDIM / 256, 256, 0, stream>>>(x, y, arg);

  const float dt = 1.0f / 16.0f;
  for (int n = 0; n < 16; ++n) {
    float t0 = dt * (float)n;
    const float ts[4] = {t0, t0 + 0.5f * dt, t0 + 0.5f * dt, t0 + dt};
    for (int s = 0; s < 4; ++s) {
      gemm1_kernel<<<512, 256, GEMM_LDS, stream>>>(arg, W1T, b1, ts[s], Hbuf);
      gemm2_kernel<<<512, 256, GEMM_LDS, stream>>>(Hbuf, W2T, part);
      combine_rk4_kernel<<<512, 256, 0, stream>>>(part, b2, y, kacc, arg, s, dt);
    }
  }
}

// Round 13
// 1245.347 us; speedup vs baseline: 1.0260x; 1.0260x over previous
//
#include <hip/hip_runtime.h>
#include <cstdint>

// ODEBlock: 16 RK4 steps of f(t,y) = tanh(y@W1 + b1 + t) @ W2 + b2
// B=1024 (M), D=512, H=2048. bf16 MFMA GEMMs, fp32 state/epilogues.
// R13 = exact revert to R11 (best: 1249us). R12's LDS-shuffle epilogue
// regressed (+29us): scattered 2B stores were already absorbed by L2 —
// write path not on the critical path. Final structure:
//  - gemm1/gemm2: 64x64 tiles, BK=128 (4 K-iters), grid 512 (2 blocks/CU),
//    XOR bank-swizzled LDS staging (R7: -168us), 64KB dbuf (R8: -131us)
//  - gemm2 split-K=4 with bf16 partials (R11: -37us)
//  - separate combine+RK4 kernel (all grid-sync fusions measured worse:
//    R3 +3.0ms, R6 +1.3ms, R9 +5.1ms)

typedef __bf16 bf16x8 __attribute__((ext_vector_type(8)));
typedef float f32x4 __attribute__((ext_vector_type(4)));

#define AS1 __attribute__((address_space(1)))
#define AS3 __attribute__((address_space(3)))

#define MDIM 1024
#define DDIM 512
#define HDIM 2048

#define GEMM_LDS (64 * 1024)   // sA 2x16KB + sB 2x16KB

__device__ __forceinline__ void async_copy16(const void* g, void* lds) {
  __builtin_amdgcn_global_load_lds((const AS1 void*)g, (AS3 void*)lds, 16, 0, 0);
}

__device__ __forceinline__ unsigned short f32_to_bf16(float f) {
  union { float f; unsigned u; } c; c.f = f;
  unsigned u = c.u + 0x7FFFu + ((c.u >> 16) & 1u);   // RNE
  return (unsigned short)(u >> 16);
}

__device__ __forceinline__ float bf16_to_f32(unsigned short h) {
  union { unsigned u; float f; } c; c.u = ((unsigned)h) << 16;
  return c.f;
}

__device__ __forceinline__ float tanh_fast(float x) {
  float a = __builtin_fabsf(x);
  float e = __expf(-2.0f * a);                        // in (0,1], no overflow
  float r = (1.0f - e) * __builtin_amdgcn_rcpf(1.0f + e);
  return __builtin_copysignf(r, x);
}

// ---- transpose + f32->bf16: out[c*R + r] = bf16(in[r*C + c]) --------------
__global__ __launch_bounds__(256) void transpose_bf16_kernel(
    const float* __restrict__ in, unsigned short* __restrict__ out, int R, int C) {
  __shared__ float tile[64][65];
  int nbc = C >> 6;
  int br = blockIdx.x / nbc, bc = blockIdx.x % nbc;
  int r0 = br * 64, c0 = bc * 64;
  int tr = threadIdx.x >> 6, tc = threadIdx.x & 63;
  for (int i = 0; i < 16; ++i) {
    int row = i * 4 + tr;
    tile[row][tc] = in[(r0 + row) * C + c0 + tc];
  }
  __syncthreads();
  for (int i = 0; i < 16; ++i) {
    int row = i * 4 + tr;
    out[(c0 + row) * R + r0 + tc] = f32_to_bf16(tile[tc][row]);
  }
}

// ---- init: y = x (fp32, lives in d_out), arg = bf16(x) --------------------
__global__ __launch_bounds__(256) void init_kernel(
    const float* __restrict__ x, float* __restrict__ y,
    unsigned short* __restrict__ arg) {
  int i = blockIdx.x * 256 + threadIdx.x;
  float v = x[i];
  y[i] = v;
  arg[i] = f32_to_bf16(v);
}

// ---- GEMM1: H = tanh(arg[1024,512] @ W1 + b1 + t) -------------------------
// W1T [2048,512] bf16 (K-contig). Tile 64x64, BK=128, 4 K-iters, grid 512
// (2 blocks/CU), 4 waves 2x2, wave 32x32, LDS dbuf 64KB. XOR-swizzled
// staging: unit u (row=u>>4, slot=u&15) holds global k-group (slot^(row&7)).
__global__ __launch_bounds__(256, 2) void gemm1_kernel(
    const unsigned short* __restrict__ A,    // arg bf16 [1024,512]
    const unsigned short* __restrict__ Bt,   // W1T bf16 [2048,512]
    const float* __restrict__ b1, float tval,
    unsigned short* __restrict__ H)          // [1024,2048] bf16
{
  extern __shared__ char ldsbuf[];
  bf16x8* sA = (bf16x8*)ldsbuf;              // 2 x 1024 units (32KB)
  bf16x8* sB = (bf16x8*)(ldsbuf + 32768);    // 2 x 1024 units (32KB)
  const int K = DDIM;
  const int NITER = 4;            // 512 / 128
  int bid = blockIdx.x;
  int bm = bid >> 5;              // 0..15
  int bn = bid & 31;              // 0..31
  int tid = threadIdx.x;
  int lane = tid & 63;
  int wid = tid >> 6;
  int l15 = lane & 15;
  int l4 = lane >> 4;
  int wm = (wid >> 1) * 32;
  int wn = (wid & 1) * 32;
  int sw = l15 & 7;               // read-side swizzle (row & 7)

  // staging: 4 units per thread per matrix (1024 units = 64 rows x 16 slots)
  const unsigned short* gA[4];
  const unsigned short* gB[4];
#pragma unroll
  for (int i = 0; i < 4; ++i) {
    int u = tid + i * 256, r = u >> 4, s = u & 15;
    int koff = ((s ^ (r & 7)) * 8);
    gA[i] = A + (size_t)(bm * 64 + r) * K + koff;
    gB[i] = Bt + (size_t)(bn * 64 + r) * K + koff;
  }
  f32x4 acc[2][2] = {};

#pragma unroll
  for (int i = 0; i < 4; ++i) {
    async_copy16(gA[i], &sA[tid + i * 256]);
    async_copy16(gB[i], &sB[tid + i * 256]);
  }

#pragma unroll 1
  for (int kt = 0; kt < NITER; ++kt) {
    int cur = kt & 1;
    __syncthreads();
    if (kt + 1 < NITER) {
      int nxt = cur ^ 1;
      int off = (kt + 1) * 128;
#pragma unroll
      for (int i = 0; i < 4; ++i) {
        async_copy16(gA[i] + off, &sA[nxt * 1024 + tid + i * 256]);
        async_copy16(gB[i] + off, &sB[nxt * 1024 + tid + i * 256]);
      }
    }
#pragma unroll
    for (int ks = 0; ks < 4; ++ks) {
      int kg = (ks * 4 + l4) ^ sw;
      bf16x8 af[2], bfr[2];
#pragma unroll
      for (int i = 0; i < 2; ++i)
        af[i] = sA[cur * 1024 + (wm + i * 16 + l15) * 16 + kg];
#pragma unroll
      for (int j = 0; j < 2; ++j)
        bfr[j] = sB[cur * 1024 + (wn + j * 16 + l15) * 16 + kg];
#pragma unroll
      for (int i = 0; i < 2; ++i)
#pragma unroll
        for (int j = 0; j < 2; ++j)
          acc[i][j] = __builtin_amdgcn_mfma_f32_16x16x32_bf16(
              af[i], bfr[j], acc[i][j], 0, 0, 0);
    }
  }
  // D(m,n): m = l4*4 + reg, n = l15
  int row0 = bm * 64 + wm + l4 * 4;
  int col0 = bn * 64 + wn + l15;
  float bias[2];
  for (int j = 0; j < 2; ++j) bias[j] = b1[col0 + j * 16] + tval;
#pragma unroll
  for (int i = 0; i < 2; ++i)
#pragma unroll
    for (int r = 0; r < 4; ++r) {
      unsigned short* Hrow = H + (size_t)(row0 + i * 16 + r) * HDIM + col0;
#pragma unroll
      for (int j = 0; j < 2; ++j)
        Hrow[j * 16] = f32_to_bf16(tanh_fast(acc[i][j][r] + bias[j]));
    }
}

// ---- GEMM2 split-K: part[s] = H[:, s*512:(s+1)*512] @ W2T'[:, chunk] ------
// W2T [512,2048] bf16. Tile 64x64, BK=128, 4 iters per 512-K chunk,
// splitK=4, grid 512. Same staging/swizzle as gemm1. Partials stored bf16.
__global__ __launch_bounds__(256, 2) void gemm2_kernel(
    const unsigned short* __restrict__ A,    // H bf16 [1024,2048]
    const unsigned short* __restrict__ Bt,   // W2T bf16 [512,2048]
    unsigned short* __restrict__ part)       // [4][1024,512] bf16
{
  extern __shared__ char ldsbuf[];
  bf16x8* sA = (bf16x8*)ldsbuf;
  bf16x8* sB = (bf16x8*)(ldsbuf + 32768);
  const int K = HDIM;
  const int NITER = 4;                 // 512 K-chunk / 128
  int bid = blockIdx.x;
  int s = bid >> 7;                    // split-K index 0..3
  int rem = bid & 127;
  int bm = rem >> 3;                   // 0..15
  int bn = rem & 7;                    // 0..7
  int tid = threadIdx.x;
  int lane = tid & 63;
  int wid = tid >> 6;
  int l15 = lane & 15;
  int l4 = lane >> 4;
  int wm = (wid >> 1) * 32;
  int wn = (wid & 1) * 32;
  int sw = l15 & 7;
  int k0 = s * 512;

  const unsigned short* gA[4];
  const unsigned short* gB[4];
#pragma unroll
  for (int i = 0; i < 4; ++i) {
    int u = tid + i * 256, r = u >> 4, sl = u & 15;
    int koff = ((sl ^ (r & 7)) * 8);
    gA[i] = A + (size_t)(bm * 64 + r) * K + k0 + koff;
    gB[i] = Bt + (size_t)(bn * 64 + r) * K + k0 + koff;
  }
  f32x4 acc[2][2] = {};

#pragma unroll
  for (int i = 0; i < 4; ++i) {
    async_copy16(gA[i], &sA[tid + i * 256]);
    async_copy16(gB[i], &sB[tid + i * 256]);
  }

#pragma unroll 1
  for (int kt = 0; kt < NITER; ++kt) {
    int cur = kt & 1;
    __syncthreads();
    if (kt + 1 < NITER) {
      int nxt = cur ^ 1;
      int off = (kt + 1) * 128;
#pragma unroll
      for (int i = 0; i < 4; ++i) {
        async_copy16(gA[i] + off, &sA[nxt * 1024 + tid + i * 256]);
        async_copy16(gB[i] + off, &sB[nxt * 1024 + tid + i * 256]);
      }
    }
#pragma unroll
    for (int ks = 0; ks < 4; ++ks) {
      int kg = (ks * 4 + l4) ^ sw;
      bf16x8 af[2], bfr[2];
#pragma unroll
      for (int i = 0; i < 2; ++i)
        af[i] = sA[cur * 1024 + (wm + i * 16 + l15) * 16 + kg];
#pragma unroll
      for (int j = 0; j < 2; ++j)
        bfr[j] = sB[cur * 1024 + (wn + j * 16 + l15) * 16 + kg];
#pragma unroll
      for (int i = 0; i < 2; ++i)
#pragma unroll
        for (int j = 0; j < 2; ++j)
          acc[i][j] = __builtin_amdgcn_mfma_f32_16x16x32_bf16(
              af[i], bfr[j], acc[i][j], 0, 0, 0);
    }
  }
  int row0 = bm * 64 + wm + l4 * 4;
  int col0 = bn * 64 + wn + l15;
  unsigned short* P = part + (size_t)s * (MDIM * DDIM);
#pragma unroll
  for (int i = 0; i < 2; ++i)
#pragma unroll
    for (int r = 0; r < 4; ++r) {
      unsigned short* Prow = P + (size_t)(row0 + i * 16 + r) * DDIM + col0;
#pragma unroll
      for (int j = 0; j < 2; ++j)
        Prow[j * 16] = f32_to_bf16(acc[i][j][r]);
    }
}

// ---- combine + RK4 epilogue (bf16 partials -> fp32 sum) -------------------
// k = p0+p1+p2+p3 + b2   (partials bf16, converted to f32, summed in f32)
// mode 0: kacc = k;            arg = bf16(y + dt/2*k)
// mode 1: kacc += 2k;          arg = bf16(y + dt/2*k)
// mode 2: kacc += 2k;          arg = bf16(y + dt*k)
// mode 3: y += dt/6*(kacc+k);  arg = bf16(y_new)
__global__ __launch_bounds__(256) void combine_rk4_kernel(
    const unsigned short* __restrict__ part,  // [4][1024*512] bf16
    const float* __restrict__ b2,
    float* __restrict__ y, float* __restrict__ kacc,
    unsigned short* __restrict__ arg, int mode, float dt)
{
  int t = blockIdx.x * 256 + threadIdx.x;    // 0..131071
  int base = t * 4;
  int col = base & (DDIM - 1);
  const ushort4* p0 = (const ushort4*)(part);
  const ushort4* p1 = (const ushort4*)(part + MDIM * DDIM);
  const ushort4* p2 = (const ushort4*)(part + 2 * MDIM * DDIM);
  const ushort4* p3 = (const ushort4*)(part + 3 * MDIM * DDIM);
  ushort4 a = p0[t], b = p1[t], c = p2[t], d = p3[t];
  float4 bb = *(const float4*)(b2 + col);
  float4 k;
  k.x = bf16_to_f32(a.x) + bf16_to_f32(b.x) + bf16_to_f32(c.x) + bf16_to_f32(d.x) + bb.x;
  k.y = bf16_to_f32(a.y) + bf16_to_f32(b.y) + bf16_to_f32(c.y) + bf16_to_f32(d.y) + bb.y;
  k.z = bf16_to_f32(a.z) + bf16_to_f32(b.z) + bf16_to_f32(c.z) + bf16_to_f32(d.z) + bb.z;
  k.w = bf16_to_f32(a.w) + bf16_to_f32(b.w) + bf16_to_f32(c.w) + bf16_to_f32(d.w) + bb.w;
  float4 yv = *(const float4*)(y + base);
  float4 argv;
  if (mode == 0) {
    *(float4*)(kacc + base) = k;
    float h = 0.5f * dt;
    argv.x = yv.x + h * k.x; argv.y = yv.y + h * k.y;
    argv.z = yv.z + h * k.z; argv.w = yv.w + h * k.w;
  } else if (mode == 1) {
    float4 ka = *(const float4*)(kacc + base);
    ka.x += 2.0f * k.x; ka.y += 2.0f * k.y; ka.z += 2.0f * k.z; ka.w += 2.0f * k.w;
    *(float4*)(kacc + base) = ka;
    float h = 0.5f * dt;
    argv.x = yv.x + h * k.x; argv.y = yv.y + h * k.y;
    argv.z = yv.z + h * k.z; argv.w = yv.w + h * k.w;
  } else if (mode == 2) {
    float4 ka = *(const float4*)(kacc + base);
    ka.x += 2.0f * k.x; ka.y += 2.0f * k.y; ka.z += 2.0f * k.z; ka.w += 2.0f * k.w;
    *(float4*)(kacc + base) = ka;
    argv.x = yv.x + dt * k.x; argv.y = yv.y + dt * k.y;
    argv.z = yv.z + dt * k.z; argv.w = yv.w + dt * k.w;
  } else {
    float4 ka = *(const float4*)(kacc + base);
    float sx = dt * (1.0f / 6.0f);
    argv.x = yv.x + sx * (ka.x + k.x); argv.y = yv.y + sx * (ka.y + k.y);
    argv.z = yv.z + sx * (ka.z + k.z); argv.w = yv.w + sx * (ka.w + k.w);
    *(float4*)(y + base) = argv;
  }
  ushort4 av;
  av.x = f32_to_bf16(argv.x); av.y = f32_to_bf16(argv.y);
  av.z = f32_to_bf16(argv.z); av.w = f32_to_bf16(argv.w);
  *(ushort4*)(arg + base) = av;
}

extern "C" void kernel_launch(void* const* d_in, const int* in_sizes, int n_in,
                              void* d_out, int out_size, void* d_ws, size_t ws_size,
                              hipStream_t stream) {
  (void)in_sizes; (void)n_in; (void)out_size; (void)ws_size;
  const float* x  = (const float*)d_in[0];   // [1024,512]
  const float* W1 = (const float*)d_in[1];   // [512,2048]
  const float* b1 = (const float*)d_in[2];   // [2048]
  const float* W2 = (const float*)d_in[3];   // [2048,512]
  const float* b2 = (const float*)d_in[4];   // [512]
  float* y = (float*)d_out;                  // fp32 state lives in d_out

  char* ws = (char*)d_ws;
  unsigned short* W1T  = (unsigned short*)(ws);                    // 2MB  [2048,512] bf16
  unsigned short* W2T  = (unsigned short*)(ws + (2u << 20));       // 2MB  [512,2048] bf16
  unsigned short* Hbuf = (unsigned short*)(ws + (4u << 20));       // 4MB  [1024,2048] bf16
  unsigned short* arg  = (unsigned short*)(ws + (8u << 20));       // 1MB  [1024,512] bf16
  float*          kacc = (float*)(ws + (9u << 20));                // 2MB  [1024,512] f32
  unsigned short* part = (unsigned short*)(ws + (11u << 20));      // 4MB  [4][1024,512] bf16
  // total 15MB

  hipFuncSetAttribute((const void*)gemm1_kernel,
                      hipFuncAttributeMaxDynamicSharedMemorySize, GEMM_LDS);
  hipFuncSetAttribute((const void*)gemm2_kernel,
                      hipFuncAttributeMaxDynamicSharedMemorySize, GEMM_LDS);

  transpose_bf16_kernel<<<256, 256, 0, stream>>>(W1, W1T, DDIM, HDIM);
  transpose_bf16_kernel<<<256, 256, 0, stream>>>(W2, W2T, HDIM, DDIM);
  init_kernel<<<MDIM * DDIM / 256, 256, 0, stream>>>(x, y, arg);

  const float dt = 1.0f / 16.0f;
  for (int n = 0; n < 16; ++n) {
    float t0 = dt * (float)n;
    const float ts[4] = {t0, t0 + 0.5f * dt, t0 + 0.5f * dt, t0 + dt};
    for (int s = 0; s < 4; ++s) {
      gemm1_kernel<<<512, 256, GEMM_LDS, stream>>>(arg, W1T, b1, ts[s], Hbuf);
      gemm2_kernel<<<512, 256, GEMM_LDS, stream>>>(Hbuf, W2T, part);
      combine_rk4_kernel<<<512, 256, 0, stream>>>(part, b2, y, kacc, arg, s, dt);
    }
  }
}